// Round 1
// baseline (49.323 us; speedup 1.0000x reference)
//
#include <hip/hip_runtime.h>

// RandomShift: out[b,t] = in[b, t - s_b] if 0 <= t - s_b < T else 0.
// B=2048, T=16000, fp32. Memory-bound: ~262 MB total traffic.

constexpr int BATCH = 2048;
constexpr int TIME = 16000;
constexpr int ELEMS_PER_THREAD = 4;
constexpr int BLOCK = 256;

__global__ __launch_bounds__(BLOCK) void random_shift_kernel(
    const float* __restrict__ in,
    const int* __restrict__ shifts,
    float* __restrict__ out) {
    const int b = blockIdx.y;
    const int s = shifts[b];  // uniform per block -> scalar
    const int t0 = (blockIdx.x * BLOCK + threadIdx.x) * ELEMS_PER_THREAD;
    if (t0 >= TIME) return;

    const float* __restrict__ row_in = in + (size_t)b * TIME;

    float4 v;
    int src = t0 - s;
    v.x = (src >= 0 && src < TIME) ? row_in[src] : 0.0f;
    ++src;
    v.y = (src >= 0 && src < TIME) ? row_in[src] : 0.0f;
    ++src;
    v.z = (src >= 0 && src < TIME) ? row_in[src] : 0.0f;
    ++src;
    v.w = (src >= 0 && src < TIME) ? row_in[src] : 0.0f;

    // t0 is a multiple of 4 and TIME % 4 == 0, so this store is in-bounds
    // and 16B-aligned.
    *reinterpret_cast<float4*>(out + (size_t)b * TIME + t0) = v;
}

extern "C" void kernel_launch(void* const* d_in, const int* in_sizes, int n_in,
                              void* d_out, int out_size, void* d_ws, size_t ws_size,
                              hipStream_t stream) {
    const float* in = (const float*)d_in[0];
    const int* shifts = (const int*)d_in[1];
    float* out = (float*)d_out;

    dim3 block(BLOCK);
    dim3 grid((TIME / ELEMS_PER_THREAD + BLOCK - 1) / BLOCK, BATCH);
    random_shift_kernel<<<grid, block, 0, stream>>>(in, shifts, out);
}

// Round 2
// 43.722 us; speedup vs baseline: 1.1281x; 1.1281x over previous
//
#include <hip/hip_runtime.h>

// RandomShift: out[b,t] = in[b, t - s_b] if 0 <= t - s_b < T else 0.
// B=2048, T=16000, fp32. Memory-bound: ~262 MB total traffic.
//
// Key structure: shift s is uniform per row (= per block), so tile validity
// is a wave-uniform predicate. Interior tiles take a fast path: one
// 4B-aligned (possibly 16B-misaligned) dwordx4 load per thread, no
// per-element bounds checks.

constexpr int BATCH = 2048;
constexpr int TIME = 16000;
constexpr int EPT = 4;            // elements per thread
constexpr int BLOCK = 256;
constexpr int TILE = BLOCK * EPT; // 1024

// float4 with only 4-byte alignment guarantee: lets the compiler emit a
// wide load at a dword-aligned (not 16B-aligned) address.
typedef float f4u __attribute__((ext_vector_type(4), aligned(4)));

__global__ __launch_bounds__(BLOCK) void random_shift_kernel(
    const float* __restrict__ in,
    const int* __restrict__ shifts,
    float* __restrict__ out) {
    const int b = blockIdx.y;
    const int s = shifts[b];  // uniform per block -> scalar
    const int tile0 = blockIdx.x * TILE;
    const int t0 = tile0 + threadIdx.x * EPT;
    if (t0 >= TIME) return;

    const float* __restrict__ row_in = in + (size_t)b * TIME;
    const int tile_end = (tile0 + TILE < TIME) ? (tile0 + TILE) : TIME;

    float4 v;
    if (tile0 - s >= 0 && tile_end - s <= TIME) {
        // Whole tile maps to valid sources: single wide load, no checks.
        f4u lv = *reinterpret_cast<const f4u*>(row_in + (t0 - s));
        v.x = lv.x; v.y = lv.y; v.z = lv.z; v.w = lv.w;
    } else {
        int src = t0 - s;
        v.x = (src >= 0 && src < TIME) ? row_in[src] : 0.0f;
        ++src;
        v.y = (src >= 0 && src < TIME) ? row_in[src] : 0.0f;
        ++src;
        v.z = (src >= 0 && src < TIME) ? row_in[src] : 0.0f;
        ++src;
        v.w = (src >= 0 && src < TIME) ? row_in[src] : 0.0f;
    }

    // t0 is a multiple of 4 and TIME % 4 == 0: in-bounds, 16B-aligned.
    *reinterpret_cast<float4*>(out + (size_t)b * TIME + t0) = v;
}

extern "C" void kernel_launch(void* const* d_in, const int* in_sizes, int n_in,
                              void* d_out, int out_size, void* d_ws, size_t ws_size,
                              hipStream_t stream) {
    const float* in = (const float*)d_in[0];
    const int* shifts = (const int*)d_in[1];
    float* out = (float*)d_out;

    dim3 block(BLOCK);
    dim3 grid((TIME + TILE - 1) / TILE, BATCH);
    random_shift_kernel<<<grid, block, 0, stream>>>(in, shifts, out);
}